// Round 1
// baseline (935.963 us; speedup 1.0000x reference)
//
#include <hip/hip_runtime.h>
#include <math.h>

#define BATCH 128

// Fused: y[b,f,n] = relu( dot(W[f*3+sel[n], :], x[b,:,n]) + bias[f*3+sel[n]] )
// out[b,f,m] = max(y[b,f,2m], y[b,f,2m+1])
// x:   [B, cin, dim]   (row-major, stride: b*cin*dim + i*dim + n)
// W:   [3*cf, cin]
// out: [B, cf, dim/2]
__global__ __launch_bounds__(256) void kdconv_kernel(
    const float* __restrict__ x,
    const float* __restrict__ W,
    const float* __restrict__ bias,
    const int*   __restrict__ sel,
    float* __restrict__ out,
    int cin, int cf, int dim)
{
    int halfd = dim >> 1;
    int total = BATCH * cf * halfd;
    int t = blockIdx.x * blockDim.x + threadIdx.x;
    if (t >= total) return;

    int m = t % halfd;
    int f = (t / halfd) % cf;
    int b = t / (halfd * cf);

    int n0 = 2 * m;
    int n1 = n0 + 1;
    int s0 = sel[n0];
    int s1 = sel[n1];
    int row0 = f * 3 + s0;   // interleaved group layout: o = f*3 + g
    int row1 = f * 3 + s1;

    const float* __restrict__ w0 = W + (size_t)row0 * cin;
    const float* __restrict__ w1 = W + (size_t)row1 * cin;
    const float* __restrict__ xb = x + (size_t)b * cin * dim;

    float acc0 = bias[row0];
    float acc1 = bias[row1];
#pragma unroll 4
    for (int i = 0; i < cin; ++i) {
        float xv0 = xb[(size_t)i * dim + n0];
        float xv1 = xb[(size_t)i * dim + n1];
        acc0 = fmaf(w0[i], xv0, acc0);
        acc1 = fmaf(w1[i], xv1, acc1);
    }
    acc0 = fmaxf(acc0, 0.0f);
    acc1 = fmaxf(acc1, 0.0f);
    out[((size_t)b * cf + f) * halfd + m] = fmaxf(acc0, acc1);
}

// h: [B, 1024], fcW: [16, 1024], fcb: [16], out: [B, 16] log-softmax
// one block (256 threads) per batch row
__global__ __launch_bounds__(256) void fc_logsoftmax_kernel(
    const float* __restrict__ h,
    const float* __restrict__ fcW,
    const float* __restrict__ fcb,
    float* __restrict__ out)
{
    int b   = blockIdx.x;
    int tid = threadIdx.x;
    int k     = tid & 15;   // output class
    int chunk = tid >> 4;   // 16 chunks of 64 elements

    const float* __restrict__ hb = h + (size_t)b * 1024;
    const float* __restrict__ wk = fcW + (size_t)k * 1024;

    float partial = 0.0f;
    int j0 = chunk * 64;
#pragma unroll 8
    for (int j = 0; j < 64; ++j)
        partial = fmaf(hb[j0 + j], wk[j0 + j], partial);

    __shared__ float red[16][17];
    red[chunk][k] = partial;
    __syncthreads();

    __shared__ float logits[16];
    if (tid < 16) {
        float s = fcb[tid];
#pragma unroll
        for (int c = 0; c < 16; ++c) s += red[c][tid];
        logits[tid] = s;
    }
    __syncthreads();

    if (tid < 16) {
        float mx = -INFINITY;
#pragma unroll
        for (int kk = 0; kk < 16; ++kk) mx = fmaxf(mx, logits[kk]);
        float se = 0.0f;
#pragma unroll
        for (int kk = 0; kk < 16; ++kk) se += expf(logits[kk] - mx);
        out[b * 16 + tid] = logits[tid] - mx - logf(se);
    }
}

static const int DIMS[11][3] = {
    {3, 8, 2048}, {8, 32, 1024}, {32, 64, 512}, {64, 64, 256}, {64, 64, 128},
    {64, 128, 64}, {128, 256, 32}, {256, 512, 16}, {512, 512, 8}, {512, 512, 4},
    {512, 1024, 2}
};

extern "C" void kernel_launch(void* const* d_in, const int* in_sizes, int n_in,
                              void* d_out, int out_size, void* d_ws, size_t ws_size,
                              hipStream_t stream)
{
    // dict order: x, (W1,b1,sel1), ..., (W11,b11,sel11), fcW, fcb
    const float* x   = (const float*)d_in[0];
    const float* fcW = (const float*)d_in[1 + 33];
    const float* fcb = (const float*)d_in[2 + 33];

    // ping-pong activation buffers in workspace (max intermediate = 2M floats = 8 MB)
    float* buf0 = (float*)d_ws;
    float* buf1 = (float*)d_ws + (2u * 1024u * 1024u);

    const float* cur = x;
    float* nxt = buf0;

    for (int li = 0; li < 11; ++li) {
        int cin = DIMS[li][0];
        int cf  = DIMS[li][1];
        int dim = DIMS[li][2];
        const float* W    = (const float*)d_in[1 + 3 * li + 0];
        const float* bias = (const float*)d_in[1 + 3 * li + 1];
        const int*   sel  = (const int*)  d_in[1 + 3 * li + 2];

        int total = BATCH * cf * (dim >> 1);
        int grid  = (total + 255) / 256;
        kdconv_kernel<<<grid, 256, 0, stream>>>(cur, W, bias, sel, nxt, cin, cf, dim);

        cur = nxt;
        nxt = (nxt == buf0) ? buf1 : buf0;
    }

    // cur now holds h: [128, 1024]
    fc_logsoftmax_kernel<<<BATCH, 256, 0, stream>>>(cur, fcW, fcb, (float*)d_out);
}

// Round 2
// 511.102 us; speedup vs baseline: 1.8313x; 1.8313x over previous
//
#include <hip/hip_runtime.h>
#include <math.h>

#define BATCH 128
#define KC 16

// ---------------- Layer 1: cin=3, cf=8, dim=2048 (input is [B,3,2048] channel-major)
// Writes X2 = [128][1024][8]  (pooled+relu'd)
__global__ __launch_bounds__(256) void layer1_kernel(
    const float* __restrict__ x, const float* __restrict__ W,
    const float* __restrict__ bias, const int* __restrict__ sel,
    float* __restrict__ Xout)
{
    __shared__ float wl[72];
    __shared__ float bl[24];
    int tid = threadIdx.x;
    if (tid < 72) wl[tid] = W[tid];
    else if (tid >= 128 && tid < 152) bl[tid - 128] = bias[tid - 128];
    __syncthreads();

    int t  = blockIdx.x * 256 + tid;   // t = b*1024 + n'
    int n2 = t & 1023;
    int b  = t >> 10;

    float res[8];
#pragma unroll
    for (int f = 0; f < 8; ++f) res[f] = -INFINITY;
#pragma unroll
    for (int p = 0; p < 2; ++p) {
        int n = 2 * n2 + p;
        int s = sel[n];
        float x0 = x[(size_t)b * 6144 + n];
        float x1 = x[(size_t)b * 6144 + 2048 + n];
        float x2 = x[(size_t)b * 6144 + 4096 + n];
#pragma unroll
        for (int f = 0; f < 8; ++f) {
            int r = f * 3 + s;
            float v = fmaf(wl[r*3+2], x2, fmaf(wl[r*3+1], x1, fmaf(wl[r*3+0], x0, bl[r])));
            res[f] = fmaxf(res[f], v);
        }
    }
    float4 o0 = {fmaxf(res[0],0.f), fmaxf(res[1],0.f), fmaxf(res[2],0.f), fmaxf(res[3],0.f)};
    float4 o1 = {fmaxf(res[4],0.f), fmaxf(res[5],0.f), fmaxf(res[6],0.f), fmaxf(res[7],0.f)};
    float4* op = (float4*)(Xout + ((size_t)b * 1024 + n2) * 8);
    op[0] = o0; op[1] = o1;
}

// ---------------- Layer 2: cin=8, cf=32, dim=1024. X2 [128][1024][8] -> X3 [128][512][32]
__global__ __launch_bounds__(256) void layer2_kernel(
    const float* __restrict__ X, const float* __restrict__ W,
    const float* __restrict__ bias, const int* __restrict__ sel,
    float* __restrict__ Xout)
{
    __shared__ float wl[96][12];   // row stride 12 -> 16B-aligned float4 reads
    __shared__ float bl[96];
    int tid = threadIdx.x;
    for (int k = tid; k < 768; k += 256) wl[k >> 3][k & 7] = W[k];
    if (tid < 96) bl[tid] = bias[tid];
    __syncthreads();

    int t  = blockIdx.x * 256 + tid;   // t = ((b*512)+n')*32 + f
    int f  = t & 31;
    int n2 = (t >> 5) & 511;
    int b  = t >> 14;

    int s0 = sel[2 * n2], s1 = sel[2 * n2 + 1];
    int r0 = f * 3 + s0, r1 = f * 3 + s1;

    const float* xr = X + ((size_t)b * 1024 + 2 * n2) * 8;
    float4 xa0 = *(const float4*)(xr + 0);
    float4 xa1 = *(const float4*)(xr + 4);
    float4 xb0 = *(const float4*)(xr + 8);
    float4 xb1 = *(const float4*)(xr + 12);
    float4 wa0 = *(const float4*)&wl[r0][0];
    float4 wa1 = *(const float4*)&wl[r0][4];
    float4 wb0 = *(const float4*)&wl[r1][0];
    float4 wb1 = *(const float4*)&wl[r1][4];

    float v0 = bl[r0] + wa0.x*xa0.x + wa0.y*xa0.y + wa0.z*xa0.z + wa0.w*xa0.w
                      + wa1.x*xa1.x + wa1.y*xa1.y + wa1.z*xa1.z + wa1.w*xa1.w;
    float v1 = bl[r1] + wb0.x*xb0.x + wb0.y*xb0.y + wb0.z*xb0.z + wb0.w*xb0.w
                      + wb1.x*xb1.x + wb1.y*xb1.y + wb1.z*xb1.z + wb1.w*xb1.w;
    Xout[((size_t)b * 512 + n2) * 32 + f] = fmaxf(fmaxf(v0, v1), 0.f);
}

// ---------------- Generic GEMM layer (layers 3..11): lane<->f (64 f per block),
// TB batch rows per thread, both positions of a pool-pair, fused bias+relu+maxpool.
// X: [128][2*np][cin], W: [3*cf][cin], Xout: [128][np][cf]
template<int TB>
__global__ __launch_bounds__(64) void kd_gemm_kernel(
    const float* __restrict__ X, const float* __restrict__ W,
    const float* __restrict__ bias, const int* __restrict__ sel,
    float* __restrict__ Xout, int cin, int cf, int np)
{
    int n    = blockIdx.x;
    int f0   = blockIdx.y << 6;
    int b0   = blockIdx.z * TB;
    int lane = threadIdx.x;

    int s0 = sel[2 * n];
    int s1 = sel[2 * n + 1];

    __shared__ float wl[2][64][20];   // stride 20 floats: 16B-aligned vec4, mild 4-way conflict

    float acc0[TB], acc1[TB];
#pragma unroll
    for (int j = 0; j < TB; ++j) { acc0[j] = 0.f; acc1[j] = 0.f; }

    size_t np2cin = (size_t)(2 * np) * cin;
    const float* xbase  = X + (size_t)(2 * n) * cin + (size_t)b0 * np2cin;
    const float* w0base = W + (size_t)(f0 * 3 + s0) * cin;
    const float* w1base = W + (size_t)(f0 * 3 + s1) * cin;

    for (int ic = 0; ic < cin; ic += KC) {
        // stage 2 x 64 rows x KC cols = 512 float4s, 8 per thread, coalesced-ish
#pragma unroll
        for (int k = 0; k < 8; ++k) {
            int v  = (k << 6) + lane;
            int c4 = v & 3;
            int r  = (v >> 2) & 63;
            const float* base = (k < 4) ? w0base : w1base;
            const float* src  = base + (size_t)(3 * r) * cin + ic + (c4 << 2);
            *(float4*)&wl[k >> 2][r][c4 << 2] = *(const float4*)src;
        }
        __syncthreads();
#pragma unroll
        for (int i4 = 0; i4 < KC / 4; ++i4) {
            float4 w0v = *(float4*)&wl[0][lane][i4 << 2];
            float4 w1v = *(float4*)&wl[1][lane][i4 << 2];
#pragma unroll
            for (int j = 0; j < TB; ++j) {
                const float* xr = xbase + (size_t)j * np2cin + ic + (i4 << 2);
                float4 x0v = *(const float4*)xr;            // wave-uniform address
                float4 x1v = *(const float4*)(xr + cin);    // wave-uniform address
                acc0[j] = fmaf(w0v.w, x0v.w, fmaf(w0v.z, x0v.z, fmaf(w0v.y, x0v.y, fmaf(w0v.x, x0v.x, acc0[j]))));
                acc1[j] = fmaf(w1v.w, x1v.w, fmaf(w1v.z, x1v.z, fmaf(w1v.y, x1v.y, fmaf(w1v.x, x1v.x, acc1[j]))));
            }
        }
        __syncthreads();
    }

    int f = f0 + lane;
    float bi0 = bias[f * 3 + s0];
    float bi1 = bias[f * 3 + s1];
#pragma unroll
    for (int j = 0; j < TB; ++j) {
        float v = fmaxf(fmaxf(acc0[j] + bi0, acc1[j] + bi1), 0.f);
        Xout[((size_t)(b0 + j) * np + n) * cf + f] = v;
    }
}

// ---------------- FC head: h [128][1024] -> log_softmax(h @ fcW^T + fcb) [128][16]
__global__ __launch_bounds__(256) void fc_logsoftmax_kernel(
    const float* __restrict__ h, const float* __restrict__ fcW,
    const float* __restrict__ fcb, float* __restrict__ out)
{
    int b   = blockIdx.x;
    int tid = threadIdx.x;
    int k     = tid & 15;
    int chunk = tid >> 4;

    const float* __restrict__ hb = h + (size_t)b * 1024;
    const float* __restrict__ wk = fcW + (size_t)k * 1024;

    float partial = 0.0f;
    int j0 = chunk * 64;
#pragma unroll 8
    for (int j = 0; j < 64; ++j)
        partial = fmaf(hb[j0 + j], wk[j0 + j], partial);

    __shared__ float red[16][17];
    red[chunk][k] = partial;
    __syncthreads();

    __shared__ float logits[16];
    if (tid < 16) {
        float s = fcb[tid];
#pragma unroll
        for (int c = 0; c < 16; ++c) s += red[c][tid];
        logits[tid] = s;
    }
    __syncthreads();

    if (tid < 16) {
        float mx = -INFINITY;
#pragma unroll
        for (int kk = 0; kk < 16; ++kk) mx = fmaxf(mx, logits[kk]);
        float se = 0.0f;
#pragma unroll
        for (int kk = 0; kk < 16; ++kk) se += expf(logits[kk] - mx);
        out[b * 16 + tid] = logits[tid] - mx - logf(se);
    }
}

static const int DIMS[11][3] = {
    {3, 8, 2048}, {8, 32, 1024}, {32, 64, 512}, {64, 64, 256}, {64, 64, 128},
    {64, 128, 64}, {128, 256, 32}, {256, 512, 16}, {512, 512, 8}, {512, 512, 4},
    {512, 1024, 2}
};

extern "C" void kernel_launch(void* const* d_in, const int* in_sizes, int n_in,
                              void* d_out, int out_size, void* d_ws, size_t ws_size,
                              hipStream_t stream)
{
    const float* x   = (const float*)d_in[0];
    const float* fcW = (const float*)d_in[34];
    const float* fcb = (const float*)d_in[35];

    float* buf0 = (float*)d_ws;
    float* buf1 = (float*)d_ws + (2u * 1024u * 1024u);   // two 8 MB buffers

    // L1: x -> buf0 (X2, [128][1024][8])
    layer1_kernel<<<512, 256, 0, stream>>>(
        x, (const float*)d_in[1], (const float*)d_in[2], (const int*)d_in[3], buf0);
    // L2: buf0 -> buf1 (X3, [128][512][32])
    layer2_kernel<<<8192, 256, 0, stream>>>(
        buf0, (const float*)d_in[4], (const float*)d_in[5], (const int*)d_in[6], buf1);

    const float* cur = buf1;
    float* nxt = buf0;
    for (int li = 2; li < 11; ++li) {
        int cin = DIMS[li][0], cf = DIMS[li][1], dim = DIMS[li][2];
        int np = dim >> 1;
        const float* W    = (const float*)d_in[1 + 3 * li];
        const float* bias = (const float*)d_in[2 + 3 * li];
        const int*   sel  = (const int*)  d_in[3 + 3 * li];

        if (li >= 8) {   // layers 9-11: few position-pairs -> smaller b-tile for parallelism
            dim3 grid(np, cf >> 6, 32);
            kd_gemm_kernel<4><<<grid, 64, 0, stream>>>(cur, W, bias, sel, nxt, cin, cf, np);
        } else {
            dim3 grid(np, cf >> 6, 16);
            kd_gemm_kernel<8><<<grid, 64, 0, stream>>>(cur, W, bias, sel, nxt, cin, cf, np);
        }
        cur = nxt;
        nxt = (nxt == buf0) ? buf1 : buf0;
    }

    // cur = X12 = h [128][1024]
    fc_logsoftmax_kernel<<<BATCH, 256, 0, stream>>>(cur, fcW, fcb, (float*)d_out);
}

// Round 3
// 341.578 us; speedup vs baseline: 2.7401x; 1.4963x over previous
//
#include <hip/hip_runtime.h>
#include <math.h>

#define BATCH 128

// ============================================================================
// Pack kernel: Wg[s][i][f] = W[(f*3+s)*cin + i]  for layers 3..8
// ============================================================================
struct PackArgs {
    const float* W[6];
    int end[6];    // cumulative element ends
    int cin[6];
    int cf[6];
};

__global__ __launch_bounds__(256) void pack_kernel(PackArgs pa, float* __restrict__ Wg, int total)
{
    int t = blockIdx.x * 256 + threadIdx.x;
    if (t >= total) return;
    int li = 0;
    while (t >= pa.end[li]) ++li;
    int base = (li == 0) ? 0 : pa.end[li - 1];
    int r = t - base;
    int cf = pa.cf[li], cin = pa.cin[li];
    int f = r % cf;
    int i = (r / cf) % cin;
    int s = r / (cf * cin);
    Wg[t] = pa.W[li][(size_t)(f * 3 + s) * cin + i];
}

// ============================================================================
// Layer 1: cin=3, cf=8, dim=2048 (input [B,3,2048] channel-major)
// -> X2 [128][1024][8]
// ============================================================================
__global__ __launch_bounds__(256) void layer1_kernel(
    const float* __restrict__ x, const float* __restrict__ W,
    const float* __restrict__ bias, const int* __restrict__ sel,
    float* __restrict__ Xout)
{
    __shared__ float wl[72];
    __shared__ float bl[24];
    int tid = threadIdx.x;
    if (tid < 72) wl[tid] = W[tid];
    else if (tid >= 128 && tid < 152) bl[tid - 128] = bias[tid - 128];
    __syncthreads();

    int t  = blockIdx.x * 256 + tid;   // t = b*1024 + n'
    int n2 = t & 1023;
    int b  = t >> 10;

    float res[8];
#pragma unroll
    for (int f = 0; f < 8; ++f) res[f] = -INFINITY;
#pragma unroll
    for (int p = 0; p < 2; ++p) {
        int n = 2 * n2 + p;
        int s = sel[n];
        float x0 = x[(size_t)b * 6144 + n];
        float x1 = x[(size_t)b * 6144 + 2048 + n];
        float x2 = x[(size_t)b * 6144 + 4096 + n];
#pragma unroll
        for (int f = 0; f < 8; ++f) {
            int r = f * 3 + s;
            float v = fmaf(wl[r*3+2], x2, fmaf(wl[r*3+1], x1, fmaf(wl[r*3+0], x0, bl[r])));
            res[f] = fmaxf(res[f], v);
        }
    }
    float4 o0 = {fmaxf(res[0],0.f), fmaxf(res[1],0.f), fmaxf(res[2],0.f), fmaxf(res[3],0.f)};
    float4 o1 = {fmaxf(res[4],0.f), fmaxf(res[5],0.f), fmaxf(res[6],0.f), fmaxf(res[7],0.f)};
    float4* op = (float4*)(Xout + ((size_t)b * 1024 + n2) * 8);
    op[0] = o0; op[1] = o1;
}

// ============================================================================
// Layer 2: cin=8, cf=32. X2 [128][1024][8] -> X3 [128][512][32]
// ============================================================================
__global__ __launch_bounds__(256) void layer2_kernel(
    const float* __restrict__ X, const float* __restrict__ W,
    const float* __restrict__ bias, const int* __restrict__ sel,
    float* __restrict__ Xout)
{
    __shared__ float wl[96][12];
    __shared__ float bl[96];
    int tid = threadIdx.x;
    for (int k = tid; k < 768; k += 256) wl[k >> 3][k & 7] = W[k];
    if (tid < 96) bl[tid] = bias[tid];
    __syncthreads();

    int t  = blockIdx.x * 256 + tid;   // t = ((b*512)+n')*32 + f
    int f  = t & 31;
    int n2 = (t >> 5) & 511;
    int b  = t >> 14;

    int s0 = sel[2 * n2], s1 = sel[2 * n2 + 1];
    int r0 = f * 3 + s0, r1 = f * 3 + s1;

    const float* xr = X + ((size_t)b * 1024 + 2 * n2) * 8;
    float4 xa0 = *(const float4*)(xr + 0);
    float4 xa1 = *(const float4*)(xr + 4);
    float4 xb0 = *(const float4*)(xr + 8);
    float4 xb1 = *(const float4*)(xr + 12);
    float4 wa0 = *(const float4*)&wl[r0][0];
    float4 wa1 = *(const float4*)&wl[r0][4];
    float4 wb0 = *(const float4*)&wl[r1][0];
    float4 wb1 = *(const float4*)&wl[r1][4];

    float v0 = bl[r0] + wa0.x*xa0.x + wa0.y*xa0.y + wa0.z*xa0.z + wa0.w*xa0.w
                      + wa1.x*xa1.x + wa1.y*xa1.y + wa1.z*xa1.z + wa1.w*xa1.w;
    float v1 = bl[r1] + wb0.x*xb0.x + wb0.y*xb0.y + wb0.z*xb0.z + wb0.w*xb0.w
                      + wb1.x*xb1.x + wb1.y*xb1.y + wb1.z*xb1.z + wb1.w*xb1.w;
    Xout[((size_t)b * 512 + n2) * 32 + f] = fmaxf(fmaxf(v0, v1), 0.f);
}

// ============================================================================
// Output-stationary layer kernel (layers 3..8), no LDS.
// lane <-> f (FV f-values per lane via vector load from packed Wg[s][cin][cf]),
// x loads are wave-uniform broadcasts. Fused bias+relu+maxpool.
// X: [128][2*NP][CIN], Wg: [3][CIN][CF], Xout: [128][NP][CF]
// ============================================================================
template<int FV>
__device__ __forceinline__ void loadv(float (&d)[FV], const float* __restrict__ p)
{
    if constexpr (FV == 1) { d[0] = *p; }
    else if constexpr (FV == 2) { float2 t = *(const float2*)p; d[0]=t.x; d[1]=t.y; }
    else { float4 t = *(const float4*)p; d[0]=t.x; d[1]=t.y; d[2]=t.z; d[3]=t.w; }
}

template<int CIN, int CF, int NP, int FV, int TB>
__global__ __launch_bounds__(64) void ostat_kernel(
    const float* __restrict__ X,
    const float* __restrict__ Wg,
    const float* __restrict__ bias,
    const int*   __restrict__ sel,
    float* __restrict__ Xout)
{
    const int n    = blockIdx.x;
    const int f0   = blockIdx.y * (64 * FV);
    const int b0   = blockIdx.z * TB;
    const int lane = threadIdx.x;
    const int f    = f0 + lane * FV;

    const int s0 = sel[2 * n];
    const int s1 = sel[2 * n + 1];

    const float* w0p = Wg + (size_t)s0 * CIN * CF + f;
    const float* w1p = Wg + (size_t)s1 * CIN * CF + f;
    const float* x0p = X + ((size_t)b0 * 2 * NP + 2 * n) * CIN;

    float acc0[TB][FV], acc1[TB][FV];
#pragma unroll
    for (int j = 0; j < TB; ++j)
#pragma unroll
        for (int v = 0; v < FV; ++v) { acc0[j][v] = 0.f; acc1[j][v] = 0.f; }

#pragma unroll 2
    for (int ic4 = 0; ic4 < CIN / 4; ++ic4) {
        float wv0[4][FV], wv1[4][FV];
#pragma unroll
        for (int k = 0; k < 4; ++k) {
            loadv<FV>(wv0[k], w0p + (size_t)(ic4 * 4 + k) * CF);
            loadv<FV>(wv1[k], w1p + (size_t)(ic4 * 4 + k) * CF);
        }
#pragma unroll
        for (int j = 0; j < TB; ++j) {
            const float* xr = x0p + (size_t)j * (2 * NP * CIN) + ic4 * 4;
            float4 xa = *(const float4*)xr;          // wave-uniform broadcast
            float4 xb = *(const float4*)(xr + CIN);  // wave-uniform broadcast
#pragma unroll
            for (int v = 0; v < FV; ++v) {
                acc0[j][v] = fmaf(wv0[0][v], xa.x, acc0[j][v]);
                acc0[j][v] = fmaf(wv0[1][v], xa.y, acc0[j][v]);
                acc0[j][v] = fmaf(wv0[2][v], xa.z, acc0[j][v]);
                acc0[j][v] = fmaf(wv0[3][v], xa.w, acc0[j][v]);
                acc1[j][v] = fmaf(wv1[0][v], xb.x, acc1[j][v]);
                acc1[j][v] = fmaf(wv1[1][v], xb.y, acc1[j][v]);
                acc1[j][v] = fmaf(wv1[2][v], xb.z, acc1[j][v]);
                acc1[j][v] = fmaf(wv1[3][v], xb.w, acc1[j][v]);
            }
        }
    }

#pragma unroll
    for (int v = 0; v < FV; ++v) {
        float bi0 = bias[(f + v) * 3 + s0];
        float bi1 = bias[(f + v) * 3 + s1];
#pragma unroll
        for (int j = 0; j < TB; ++j) {
            float val = fmaxf(fmaxf(acc0[j][v] + bi0, acc1[j][v] + bi1), 0.f);
            Xout[((size_t)(b0 + j) * NP + n) * CF + f + v] = val;
        }
    }
}

// ============================================================================
// Wave-row kernel (layers 9..11, CIN=512): wave per (b, n, 16-f chunk),
// lane <-> cin slice (8 floats). W read coalesced in ORIGINAL layout.
// Cross-lane reduce via LDS transpose + 2 shuffles.
// ============================================================================
__device__ __forceinline__ float dot8(float4 a0, float4 a1, float4 b0, float4 b1)
{
    float s = a0.x * b0.x;
    s = fmaf(a0.y, b0.y, s);
    s = fmaf(a0.z, b0.z, s);
    s = fmaf(a0.w, b0.w, s);
    s = fmaf(a1.x, b1.x, s);
    s = fmaf(a1.y, b1.y, s);
    s = fmaf(a1.z, b1.z, s);
    s = fmaf(a1.w, b1.w, s);
    return s;
}

template<int CF, int NP>
__global__ __launch_bounds__(256) void waverow_kernel(
    const float* __restrict__ X,     // [128][2*NP][512]
    const float* __restrict__ W,     // [3*CF][512]
    const float* __restrict__ bias,
    const int*   __restrict__ sel,
    float* __restrict__ Xout)        // [128][NP][CF]
{
    constexpr int FB = 16;
    constexpr int FCH = CF / FB;
    const int wid  = threadIdx.x >> 6;
    const int lane = threadIdx.x & 63;
    const int u = blockIdx.x * 4 + wid;
    const int fchunk = u % FCH;
    const int n = (u / FCH) % NP;
    const int b = u / (FCH * NP);

    const int s0 = sel[2 * n];
    const int s1 = sel[2 * n + 1];

    const float* xp = X + ((size_t)b * 2 * NP + 2 * n) * 512 + lane * 8;
    float4 xa0 = *(const float4*)xp;
    float4 xa1 = *(const float4*)(xp + 4);
    float4 xb0 = *(const float4*)(xp + 512);
    float4 xb1 = *(const float4*)(xp + 516);

    float acc[2 * FB];
#pragma unroll
    for (int fi = 0; fi < FB; ++fi) {
        int f = fchunk * FB + fi;
        const float* w0 = W + (size_t)(f * 3 + s0) * 512 + lane * 8;
        const float* w1 = W + (size_t)(f * 3 + s1) * 512 + lane * 8;
        float4 wa0 = *(const float4*)w0;
        float4 wa1 = *(const float4*)(w0 + 4);
        float4 wb0 = *(const float4*)w1;
        float4 wb1 = *(const float4*)(w1 + 4);
        acc[2 * fi]     = dot8(wa0, wa1, xa0, xa1);
        acc[2 * fi + 1] = dot8(wb0, wb1, xb0, xb1);
    }

    // reduce each of the 32 partials across 64 lanes
    __shared__ float red[4][64][33];
#pragma unroll
    for (int a = 0; a < 32; ++a) red[wid][lane][a] = acc[a];
    __syncthreads();

    int a    = lane >> 1;
    int half = lane & 1;
    float s = 0.f;
#pragma unroll
    for (int r = 0; r < 32; ++r) s += red[wid][(half << 5) | r][a];
    s += __shfl_xor(s, 1, 64);          // lanes 2a,2a+1 now hold full sum of acc a
    float other = __shfl_xor(s, 2, 64); // fetch partner position's sum

    if ((lane & 3) == 0) {
        int fi = lane >> 2;             // 0..15
        int f = fchunk * FB + fi;
        float v0 = s + bias[f * 3 + s0];
        float v1 = other + bias[f * 3 + s1];
        Xout[((size_t)b * NP + n) * CF + f] = fmaxf(fmaxf(v0, v1), 0.f);
    }
}

// ============================================================================
// FC head: h [128][1024] -> log_softmax(h @ fcW^T + fcb) [128][16]
// ============================================================================
__global__ __launch_bounds__(256) void fc_logsoftmax_kernel(
    const float* __restrict__ h, const float* __restrict__ fcW,
    const float* __restrict__ fcb, float* __restrict__ out)
{
    int b   = blockIdx.x;
    int tid = threadIdx.x;
    int k     = tid & 15;
    int chunk = tid >> 4;

    const float* __restrict__ hb = h + (size_t)b * 1024;
    const float* __restrict__ wk = fcW + (size_t)k * 1024;

    float partial = 0.0f;
    int j0 = chunk * 64;
#pragma unroll 8
    for (int j = 0; j < 64; ++j)
        partial = fmaf(hb[j0 + j], wk[j0 + j], partial);

    __shared__ float red[16][17];
    red[chunk][k] = partial;
    __syncthreads();

    __shared__ float logits[16];
    if (tid < 16) {
        float sum = fcb[tid];
#pragma unroll
        for (int c = 0; c < 16; ++c) sum += red[c][tid];
        logits[tid] = sum;
    }
    __syncthreads();

    if (tid < 16) {
        float mx = -INFINITY;
#pragma unroll
        for (int kk = 0; kk < 16; ++kk) mx = fmaxf(mx, logits[kk]);
        float se = 0.0f;
#pragma unroll
        for (int kk = 0; kk < 16; ++kk) se += expf(logits[kk] - mx);
        out[b * 16 + tid] = logits[tid] - mx - logf(se);
    }
}

// ============================================================================
extern "C" void kernel_launch(void* const* d_in, const int* in_sizes, int n_in,
                              void* d_out, int out_size, void* d_ws, size_t ws_size,
                              hipStream_t stream)
{
    const float* x   = (const float*)d_in[0];
    const float* fcW = (const float*)d_in[34];
    const float* fcb = (const float*)d_in[35];

    float* buf0 = (float*)d_ws;
    float* buf1 = (float*)d_ws + (2u * 1024u * 1024u);
    float* Wg   = (float*)d_ws + (4u * 1024u * 1024u);   // packed W for layers 3..8

    // ---- pack W for layers 3..8 into Wg[s][cin][cf] ----
    // layer elems: L3 6144, L4 12288, L5 12288, L6 24576, L7 98304, L8 393216
    PackArgs pa;
    static const int pcin[6] = {32, 64, 64, 64, 128, 256};
    static const int pcf[6]  = {64, 64, 64, 128, 256, 512};
    int acc_end = 0;
    for (int i = 0; i < 6; ++i) {
        pa.W[i] = (const float*)d_in[1 + 3 * (i + 2)];
        pa.cin[i] = pcin[i];
        pa.cf[i]  = pcf[i];
        acc_end += 3 * pcin[i] * pcf[i];
        pa.end[i] = acc_end;
    }
    const int pack_total = acc_end;  // 546816
    pack_kernel<<<(pack_total + 255) / 256, 256, 0, stream>>>(pa, Wg, pack_total);

    // Wg per-layer offsets
    int wg_off[6];
    wg_off[0] = 0;
    for (int i = 1; i < 6; ++i) wg_off[i] = pa.end[i - 1];

    // ---- L1, L2 ----
    layer1_kernel<<<512, 256, 0, stream>>>(
        x, (const float*)d_in[1], (const float*)d_in[2], (const int*)d_in[3], buf0);
    layer2_kernel<<<8192, 256, 0, stream>>>(
        buf0, (const float*)d_in[4], (const float*)d_in[5], (const int*)d_in[6], buf1);

    // ---- L3..L8 (ostat) ----
    const float* b3 = (const float*)d_in[8];  const int* s3 = (const int*)d_in[9];
    const float* b4 = (const float*)d_in[11]; const int* s4 = (const int*)d_in[12];
    const float* b5 = (const float*)d_in[14]; const int* s5 = (const int*)d_in[15];
    const float* b6 = (const float*)d_in[17]; const int* s6 = (const int*)d_in[18];
    const float* b7 = (const float*)d_in[20]; const int* s7 = (const int*)d_in[21];
    const float* b8 = (const float*)d_in[23]; const int* s8 = (const int*)d_in[24];

    ostat_kernel<32, 64, 256, 1, 8><<<dim3(256, 1, 16), 64, 0, stream>>>(buf1, Wg + wg_off[0], b3, s3, buf0);
    ostat_kernel<64, 64, 128, 1, 8><<<dim3(128, 1, 16), 64, 0, stream>>>(buf0, Wg + wg_off[1], b4, s4, buf1);
    ostat_kernel<64, 64, 64, 1, 4><<<dim3(64, 1, 32), 64, 0, stream>>>(buf1, Wg + wg_off[2], b5, s5, buf0);
    ostat_kernel<64, 128, 32, 1, 4><<<dim3(32, 2, 32), 64, 0, stream>>>(buf0, Wg + wg_off[3], b6, s6, buf1);
    ostat_kernel<128, 256, 16, 2, 2><<<dim3(16, 2, 64), 64, 0, stream>>>(buf1, Wg + wg_off[4], b7, s7, buf0);
    ostat_kernel<256, 512, 8, 2, 2><<<dim3(8, 4, 64), 64, 0, stream>>>(buf0, Wg + wg_off[5], b8, s8, buf1);

    // ---- L9..L11 (waverow, original W layout) ----
    // L9: units = 128*4*(512/16) = 16384 -> 4096 blocks
    waverow_kernel<512, 4><<<4096, 256, 0, stream>>>(
        buf1, (const float*)d_in[25], (const float*)d_in[26], (const int*)d_in[27], buf0);
    // L10: units = 128*2*32 = 8192 -> 2048 blocks
    waverow_kernel<512, 2><<<2048, 256, 0, stream>>>(
        buf0, (const float*)d_in[28], (const float*)d_in[29], (const int*)d_in[30], buf1);
    // L11: units = 128*1*64 = 8192 -> 2048 blocks
    waverow_kernel<1024, 1><<<2048, 256, 0, stream>>>(
        buf1, (const float*)d_in[31], (const float*)d_in[32], (const int*)d_in[33], buf0);

    // ---- FC head ----
    fc_logsoftmax_kernel<<<BATCH, 256, 0, stream>>>(buf0, fcW, fcb, (float*)d_out);
}